// Round 3
// baseline (422.119 us; speedup 1.0000x reference)
//
#include <hip/hip_runtime.h>
#include <cmath>

// K[n,m] = sv^2 * sum_p (x1[n,p]-off)*(x2[m,p]-off) + sb^2
// N = M = 8192, P = 16. Output fp32 256 MB -> write-BW-bound (~45 us floor).
//
// Streaming design: block = 16 rows x full 8192 cols, 512 threads, looping
// 16 chunks of 512 cols. x1 rows held in registers (a[4][16] per thread,
// uniform across tx lanes); x2 chunk staged TRANSPOSED in LDS ([p][col],
// stride 516 -> <=2-way bank alias = free). Each thread: 4 rows x 4 cols
// per chunk. Nontemporal float4 stores stream continuously (fill-like).

#define ROWS  16
#define CHUNK 512
#define LDST  516   // padded col stride (floats) for s2[p][col]

typedef float floatx4 __attribute__((ext_vector_type(4)));  // native vec for nontemporal builtin

__global__ __launch_bounds__(512, 4) void linear_kernel(
    const float* __restrict__ x1, const float* __restrict__ x2,
    const float* __restrict__ p_lsb, const float* __restrict__ p_lsv,
    const float* __restrict__ p_off, float* __restrict__ out, int M)
{
    __shared__ float s2[16 * LDST];   // 33 KB

    const int tid = threadIdx.x;
    const int tx = tid & 127;         // 128 col-groups x 4 cols = 512 cols
    const int ty = tid >> 7;          // 4 row-groups x 4 rows = 16 rows
    const int n0 = blockIdx.x * ROWS;

    const float off = p_off[0];
    const float sb  = expf(p_lsb[0]);
    const float sv  = expf(p_lsv[0]);
    const float sv2 = sv * sv;
    const float sb2 = sb * sb;

    // ---- x1 rows for this thread -> registers (offset-subtracted) ----
    // rows n0+ty*4 .. +3; same rows re-read by all 128 tx-threads (L1 hit).
    float a[4][16];
    #pragma unroll
    for (int r = 0; r < 4; ++r) {
        const float4* g = (const float4*)(x1 + (size_t)(n0 + ty * 4 + r) * 16);
        #pragma unroll
        for (int q = 0; q < 4; ++q) {
            float4 v = g[q];
            a[r][q * 4 + 0] = v.x - off;
            a[r][q * 4 + 1] = v.y - off;
            a[r][q * 4 + 2] = v.z - off;
            a[r][q * 4 + 3] = v.w - off;
        }
    }

    const int nchunks = M / CHUNK;    // 16
    for (int ch = 0; ch < nchunks; ++ch) {
        const int m0 = ch * CHUNK;

        // ---- stage x2[m0..m0+511][0..15] transposed into LDS ----
        // 2048 float4 items, linear (perfectly coalesced 16B/lane loads).
        const float4* g2 = (const float4*)(x2 + (size_t)m0 * 16);
        #pragma unroll
        for (int i = 0; i < 4; ++i) {
            const int j   = i * 512 + tid;
            const int row = j >> 2;
            const int p0  = (j & 3) * 4;
            float4 v = g2[j];
            s2[(p0 + 0) * LDST + row] = v.x - off;
            s2[(p0 + 1) * LDST + row] = v.y - off;
            s2[(p0 + 2) * LDST + row] = v.z - off;
            s2[(p0 + 3) * LDST + row] = v.w - off;
        }
        __syncthreads();

        // ---- rank-16 accumulation, 4x4 per thread ----
        float acc[4][4];
        #pragma unroll
        for (int r = 0; r < 4; ++r)
            #pragma unroll
            for (int c = 0; c < 4; ++c) acc[r][c] = 0.0f;

        #pragma unroll
        for (int p = 0; p < 16; ++p) {
            const float4 b = *(const float4*)&s2[p * LDST + tx * 4];
            const float bv[4] = {b.x, b.y, b.z, b.w};
            #pragma unroll
            for (int r = 0; r < 4; ++r)
                #pragma unroll
                for (int c = 0; c < 4; ++c)
                    acc[r][c] += a[r][p] * bv[c];
        }

        // barrier BEFORE stores: LDS reads done, next chunk may overwrite;
        // the vmcnt(0) drain here catches long-retired previous stores.
        __syncthreads();

        // ---- epilogue: nontemporal streaming stores ----
        // wave = 64 consecutive tx -> each store is 1 KB contiguous.
        #pragma unroll
        for (int r = 0; r < 4; ++r) {
            floatx4 o;
            o.x = sv2 * acc[r][0] + sb2;
            o.y = sv2 * acc[r][1] + sb2;
            o.z = sv2 * acc[r][2] + sb2;
            o.w = sv2 * acc[r][3] + sb2;
            floatx4* dst = (floatx4*)(out + (size_t)(n0 + ty * 4 + r) * (size_t)M
                                          + m0 + tx * 4);
            __builtin_nontemporal_store(o, dst);
        }
    }
}

extern "C" void kernel_launch(void* const* d_in, const int* in_sizes, int n_in,
                              void* d_out, int out_size, void* d_ws, size_t ws_size,
                              hipStream_t stream) {
    const float* x1  = (const float*)d_in[0];
    const float* x2  = (const float*)d_in[1];
    const float* lsb = (const float*)d_in[2];
    const float* lsv = (const float*)d_in[3];
    const float* off = (const float*)d_in[4];
    float* out = (float*)d_out;

    const int n = in_sizes[0] / 16;   // 8192
    const int m = in_sizes[1] / 16;   // 8192

    linear_kernel<<<n / ROWS, 512, 0, stream>>>(x1, x2, lsb, lsv, off, out, m);
}